// Round 8
// baseline (147.616 us; speedup 1.0000x reference)
//
#include <hip/hip_runtime.h>

// Round 8: BISECT hybrid. Round-4 kernel (passed, 113.8us) with ONLY
// P2(hbox15 lum)+P3(vbox15 mean + d) replaced by MFMA GEMMs G1+G2 vs a
// constant band matrix. P4/P5/P6a/P6b are round-4 verbatim (strides renamed).
//  G1: Hl^T = (Lum x Band)^T   stored sT1[j][m] (stride ST=104)
//  G2: mean = (BandT x Hl)/225; d=(lum-mean)^2 -> sDC row-major (stride SD=88)
// BandT[a][b] = 1 iff a<=b<=a+14 (zero-padded box15 semantics).
// sDC: d stored cols 0..87 (j<88 mask), rows 0..95; P4 consumes rows 0..81,
// windows reach col<=85 for junk-only outputs (cols 84..87 finite garbage).
// LDS 76832 B -> 2 blocks/CU.

#define BLOCK 512
typedef unsigned short u16;
typedef unsigned int u32;
typedef __attribute__((ext_vector_type(2))) float f32x2;
typedef __attribute__((ext_vector_type(4))) float f32x4;
typedef __attribute__((ext_vector_type(8))) short bf16x8;

#define SL 104   // sLum / sBT u16 stride
#define ST 104   // sT1 u16 stride
#define SD 88    // sDC u16 stride

__device__ __forceinline__ float blo(u32 u){ return __uint_as_float(u << 16); }
__device__ __forceinline__ float bhi(u32 u){ return __uint_as_float(u & 0xffff0000u); }
__device__ __forceinline__ float bf2f(u16 h){ return __uint_as_float(((u32)h) << 16); }
__device__ __forceinline__ u32 pk2(float lo, float hi){
    u32 r; asm("v_cvt_pk_bf16_f32 %0, %1, %2" : "=v"(r) : "v"(lo), "v"(hi)); return r;
}
__device__ __forceinline__ f32x2 pka(f32x2 a, f32x2 b){
    f32x2 d; asm("v_pk_add_f32 %0, %1, %2" : "=v"(d) : "v"(a), "v"(b)); return d;
}
__device__ __forceinline__ f32x2 up2(u32 u){
    f32x2 r; r.x = __uint_as_float(u << 16); r.y = __uint_as_float(u & 0xffff0000u); return r;
}
__device__ __forceinline__ float sigf(float x){ return 1.f / (1.f + __expf(-x)); }
__device__ __forceinline__ float clamp01(float x){ return fminf(fmaxf(x, 0.f), 1.f); }
__device__ __forceinline__ void unp8(uint4 v, float* o){
    o[0]=blo(v.x); o[1]=bhi(v.x); o[2]=blo(v.y); o[3]=bhi(v.y);
    o[4]=blo(v.z); o[5]=bhi(v.z); o[6]=blo(v.w); o[7]=bhi(v.w);
}
__device__ __forceinline__ float satm(float r_, float g_, float b_){
    float mx = fmaxf(r_, fmaxf(g_, b_));
    float mn = fminf(r_, fminf(g_, b_));
    float sat = (mx - mn) / (mx + 1e-8f);
    return sigf((0.3f - sat) * 10.f);
}
__device__ __forceinline__ f32x4 mf(bf16x8 a, bf16x8 b, f32x4 c){
    return __builtin_amdgcn_mfma_f32_16x16x32_bf16(a, b, c, 0, 0, 0);
}

template<bool EDGE>
__device__ __forceinline__ void body(const float* __restrict__ pR,
                                     const float* __restrict__ pG,
                                     const float* __restrict__ pB,
                                     float* __restrict__ po,
                                     int oy, int ox, int tid,
                                     u16* sLum, u16* sBT, u16* sT1, u16* sDC)
{
    const int lane = tid & 63, wid = tid >> 6;
    const int lrow = lane & 15, lgrp = lane >> 4;
    const float C225 = 1.f / 225.f;
    const float CF   = 50.f / 225.f;

    // ---- P1: lum bf16, 96 rows x 6 groups of 16 cols (r4 verbatim) ----
    for (int task = tid; task < 96 * 6; task += BLOCK) {
        int r = task / 6, c = task - r * 6;
        int gy = oy - 16 + r;
        int gxb = ox - 16 + 16 * c;
        u32 pk[8];
        #pragma unroll
        for (int sq = 0; sq < 4; ++sq) {
            int gx = gxb + 4 * sq;
            float l0 = 0.f, l1 = 0.f, l2 = 0.f, l3 = 0.f;
            if (!EDGE || ((unsigned)gy < 1024u && (unsigned)gx < 1024u)) {
                int idx = gy * 1024 + gx;
                float4 R  = *(const float4*)&pR[idx];
                float4 G  = *(const float4*)&pG[idx];
                float4 Bc = *(const float4*)&pB[idx];
                l0 = fmaf(0.299f, R.x, fmaf(0.587f, G.x, 0.114f * Bc.x));
                l1 = fmaf(0.299f, R.y, fmaf(0.587f, G.y, 0.114f * Bc.y));
                l2 = fmaf(0.299f, R.z, fmaf(0.587f, G.z, 0.114f * Bc.z));
                l3 = fmaf(0.299f, R.w, fmaf(0.587f, G.w, 0.114f * Bc.w));
            }
            pk[2 * sq]     = pk2(l0, l1);
            pk[2 * sq + 1] = pk2(l2, l3);
        }
        u16* dst = &sLum[r * SL + 16 * c];
        *(uint4*)dst     = make_uint4(pk[0], pk[1], pk[2], pk[3]);
        *(uint4*)(dst+8) = make_uint4(pk[4], pk[5], pk[6], pk[7]);
    }
    // ---- P1b: band fill: BandT[a][b] = 1.0bf16 iff a <= b <= a+14 ----
    for (int idx = tid; idx < 96 * 12; idx += BLOCK) {
        int a = idx / 12, c8 = idx - a * 12;
        int b0 = 8 * c8;
        u32 w[4];
        #pragma unroll
        for (int p = 0; p < 4; ++p) {
            int b = b0 + 2 * p;
            u32 lo = (b   >= a && b   <= a + 14) ? 0x3F80u : 0u;
            u32 hi = (b+1 >= a && b+1 <= a + 14) ? 0x3F80u : 0u;
            w[p] = lo | (hi << 16);
        }
        *(uint4*)&sBT[a * SL + b0] = make_uint4(w[0], w[1], w[2], w[3]);
    }
    __syncthreads();

    // ---- G1 (MFMA): Hl^T[j][m] = sum_c Lum[m][c]*BandT[j][c] -> sT1 ----
    for (int t = wid; t < 36; t += 8) {
        int mt = t / 6, nt = t - mt * 6;
        const u16* ap = &sLum[(mt * 16 + lrow) * SL + lgrp * 8];
        const u16* bp = &sBT [(nt * 16 + lrow) * SL + lgrp * 8];
        f32x4 acc = {0.f, 0.f, 0.f, 0.f};
        acc = mf(*(const bf16x8*)ap,        *(const bf16x8*)bp,        acc);
        acc = mf(*(const bf16x8*)(ap + 32), *(const bf16x8*)(bp + 32), acc);
        acc = mf(*(const bf16x8*)(ap + 64), *(const bf16x8*)(bp + 64), acc);
        int j = nt * 16 + lrow, i0 = mt * 16 + lgrp * 4;
        bool jv = j < 82;
        float h0 = jv ? acc[0] : 0.f, h1 = jv ? acc[1] : 0.f;
        float h2 = jv ? acc[2] : 0.f, h3 = jv ? acc[3] : 0.f;
        *(uint2*)&sT1[j * ST + i0] = make_uint2(pk2(h0, h1), pk2(h2, h3));
    }
    __syncthreads();

    // ---- G2 (MFMA): mean=(BandT x Hl)/225; d=(lum-mean)^2 -> sDC ----
    for (int t = wid; t < 36; t += 8) {
        int mt = t / 6, nt = t - mt * 6;
        const u16* ap = &sBT[(mt * 16 + lrow) * SL + lgrp * 8];
        const u16* bp = &sT1[(nt * 16 + lrow) * ST + lgrp * 8];
        f32x4 acc = {0.f, 0.f, 0.f, 0.f};
        acc = mf(*(const bf16x8*)ap,        *(const bf16x8*)bp,        acc);
        acc = mf(*(const bf16x8*)(ap + 32), *(const bf16x8*)(bp + 32), acc);
        acc = mf(*(const bf16x8*)(ap + 64), *(const bf16x8*)(bp + 64), acc);
        int j = nt * 16 + lrow, ib = mt * 16 + lgrp * 4;
        int jc = min(j + 7, 95);
        #pragma unroll
        for (int r = 0; r < 4; ++r) {
            int i = ib + r;
            float mean = acc[r] * C225;
            float l = bf2f(sLum[min(i + 7, 95) * SL + jc]);
            float tt = l - mean;
            float dv = tt * tt;
            if (EDGE) {
                int gy = oy - 9 + i, gx = ox - 9 + j;
                if (!((unsigned)gy < 1024u && (unsigned)gx < 1024u)) dv = 0.f;
            }
            if (j < SD) sDC[i * SD + j] = (u16)pk2(dv, dv);
        }
    }
    __syncthreads();

    // ---- P4: hbox15(d) -> sT1 bf16; 82 rows x 6 groups of 12 (r4 verbatim) ----
    for (int task = tid; task < 82 * 6; task += BLOCK) {
        int r = task / 6, g = task - r * 6;
        int s0 = 12 * g, c0 = s0 & ~7;
        const u16* dr = &sDC[r * SD + c0];
        float lv[32];
        unp8(*(const uint4*)dr,        lv);
        unp8(*(const uint4*)(dr + 8),  lv + 8);
        unp8(*(const uint4*)(dr + 16), lv + 16);
        unp8(*(const uint4*)(dr + 24), lv + 24);
        if (s0 & 4) {
            #pragma unroll
            for (int i = 0; i < 28; ++i) lv[i] = lv[i + 4];
        }
        float o[12];
        float s = 0.f;
        #pragma unroll
        for (int k = 0; k < 15; ++k) s += lv[k];
        o[0] = s;
        #pragma unroll
        for (int j = 1; j < 12; ++j) { s += lv[j + 14] - lv[j - 1]; o[j] = s; }
        u16* dst = &sT1[r * ST + s0];
        *(uint2*)dst       = make_uint2(pk2(o[0], o[1]),  pk2(o[2], o[3]));
        *(uint2*)(dst + 4) = make_uint2(pk2(o[4], o[5]),  pk2(o[6], o[7]));
        *(uint2*)(dst + 8) = make_uint2(pk2(o[8], o[9]),  pk2(o[10], o[11]));
    }
    __syncthreads();

    // ---- P5: var via pk-vbox15; comb bf16 -> sDC (r4 verbatim) ----
    for (int task = tid; task < 289; task += BLOCK) {
        int rg = task / 17, q = task - rg * 17;
        int r0 = 4 * rg, c0v = 4 * q;
        const u16* hp = &sT1[r0 * ST + c0v];
        f32x2 cs0, cs1, n00,n01, n10,n11, n20,n21;
        {
            uint2 v = *(const uint2*)hp;
            cs0 = up2(v.x); cs1 = up2(v.y);
            n00 = -cs0; n01 = -cs1;
        }
        {
            uint2 v = *(const uint2*)(hp + ST);
            f32x2 e0 = up2(v.x), e1 = up2(v.y);
            n10 = -e0; n11 = -e1;
            cs0 = pka(cs0, e0); cs1 = pka(cs1, e1);
        }
        {
            uint2 v = *(const uint2*)(hp + 2 * ST);
            f32x2 e0 = up2(v.x), e1 = up2(v.y);
            n20 = -e0; n21 = -e1;
            cs0 = pka(cs0, e0); cs1 = pka(cs1, e1);
        }
        #pragma unroll
        for (int k = 3; k < 15; ++k) {
            uint2 v = *(const uint2*)(hp + k * ST);
            cs0 = pka(cs0, up2(v.x)); cs1 = pka(cs1, up2(v.y));
        }
        auto emitC = [&](int row) {
            float cm0 = sigf(fmaf(cs0.x, CF, -0.5f));
            float cm1 = sigf(fmaf(cs0.y, CF, -0.5f));
            float cm2 = sigf(fmaf(cs1.x, CF, -0.5f));
            float cm3 = sigf(fmaf(cs1.y, CF, -0.5f));
            const u16* lp = &sLum[(row + 14) * SL + c0v + 12];
            ushort4 A  = *(const ushort4*)lp;
            ushort4 Bv = *(const ushort4*)(lp + 4);
            float bm0 = sigf((bf2f(A.z)  - 0.7f) * 10.f);
            float bm1 = sigf((bf2f(A.w)  - 0.7f) * 10.f);
            float bm2 = sigf((bf2f(Bv.x) - 0.7f) * 10.f);
            float bm3 = sigf((bf2f(Bv.y) - 0.7f) * 10.f);
            int gy = oy - 2 + row, gx0 = ox - 2 + c0v;
            int i0 = gy * 1024 + gx0;
            float2 z2 = make_float2(0.f, 0.f);
            float2 Ra, Rb, Ga, Gb, Ba, Bb;
            bool va = true, vb = true;
            if (EDGE) {
                bool vy = (unsigned)gy < 1024u;
                va = vy && (unsigned)gx0 < 1024u;
                vb = vy && (unsigned)(gx0 + 2) < 1024u;
                Ra = va ? *(const float2*)&pR[i0]     : z2;
                Rb = vb ? *(const float2*)&pR[i0 + 2] : z2;
                Ga = va ? *(const float2*)&pG[i0]     : z2;
                Gb = vb ? *(const float2*)&pG[i0 + 2] : z2;
                Ba = va ? *(const float2*)&pB[i0]     : z2;
                Bb = vb ? *(const float2*)&pB[i0 + 2] : z2;
            } else {
                Ra = *(const float2*)&pR[i0];  Rb = *(const float2*)&pR[i0 + 2];
                Ga = *(const float2*)&pG[i0];  Gb = *(const float2*)&pG[i0 + 2];
                Ba = *(const float2*)&pB[i0];  Bb = *(const float2*)&pB[i0 + 2];
            }
            float cb0 = clamp01(bm0 + 0.5f * cm0 * satm(Ra.x, Ga.x, Ba.x));
            float cb1 = clamp01(bm1 + 0.5f * cm1 * satm(Ra.y, Ga.y, Ba.y));
            float cb2 = clamp01(bm2 + 0.5f * cm2 * satm(Rb.x, Gb.x, Bb.x));
            float cb3 = clamp01(bm3 + 0.5f * cm3 * satm(Rb.y, Gb.y, Bb.y));
            if (EDGE) {
                cb0 = va ? cb0 : 0.f;  cb1 = va ? cb1 : 0.f;
                cb2 = vb ? cb2 : 0.f;  cb3 = vb ? cb3 : 0.f;
            }
            *(uint2*)&sDC[row * SD + c0v] = make_uint2(pk2(cb0,cb1), pk2(cb2,cb3));
        };
        emitC(r0);
        {
            uint2 v = *(const uint2*)(hp + 15 * ST);
            cs0 = pka(pka(cs0, up2(v.x)), n00); cs1 = pka(pka(cs1, up2(v.y)), n01);
        }
        emitC(r0 + 1);
        {
            uint2 v = *(const uint2*)(hp + 16 * ST);
            cs0 = pka(pka(cs0, up2(v.x)), n10); cs1 = pka(pka(cs1, up2(v.y)), n11);
        }
        emitC(r0 + 2);
        {
            uint2 v = *(const uint2*)(hp + 17 * ST);
            cs0 = pka(pka(cs0, up2(v.x)), n20); cs1 = pka(pka(cs1, up2(v.y)), n21);
        }
        emitC(r0 + 3);
    }
    __syncthreads();

    // ---- P6a: hpool5(comb) -> sT1 bf16; 68 rows x 4 groups of 16 (r4) ----
    for (int task = tid; task < 68 * 4; task += BLOCK) {
        int r = task >> 2, g = task & 3;
        int s0 = 16 * g;
        const u16* cr = &sDC[r * SD + s0];
        float cv[24];
        unp8(*(const uint4*)cr,        cv);
        unp8(*(const uint4*)(cr + 8),  cv + 8);
        unp8(*(const uint4*)(cr + 16), cv + 16);
        float o[16];
        float s = cv[0] + cv[1] + cv[2] + cv[3] + cv[4];
        o[0] = s;
        #pragma unroll
        for (int j = 1; j < 16; ++j) { s += cv[j + 4] - cv[j - 1]; o[j] = s; }
        u16* dst = &sT1[r * ST + s0];
        *(uint4*)dst = make_uint4(pk2(o[0], o[1]), pk2(o[2], o[3]),
                                  pk2(o[4], o[5]), pk2(o[6], o[7]));
        *(uint4*)(dst + 8) = make_uint4(pk2(o[8],  o[9]),  pk2(o[10], o[11]),
                                        pk2(o[12], o[13]), pk2(o[14], o[15]));
    }
    __syncthreads();

    // ---- P6b: vpool5 -> out; 16 row-groups of 4 x 16 col-quads (r4) ----
    for (int task = tid; task < 256; task += BLOCK) {
        int rg = task >> 4, q = task & 15;
        int r0 = 4 * rg, c0v = 4 * q;
        const u16* hp = &sT1[r0 * ST + c0v];
        f32x2 cs0, cs1, a00, a01, a10, a11, a20, a21;
        #pragma unroll
        for (int k = 0; k < 5; ++k) {
            uint2 v = *(const uint2*)(hp + k * ST);
            f32x2 x0 = up2(v.x), x1 = up2(v.y);
            if (k == 0) { cs0 = x0; cs1 = x1; a00 = x0; a01 = x1; }
            else {
                if (k == 1) { a10 = x0; a11 = x1; }
                if (k == 2) { a20 = x0; a21 = x1; }
                cs0 = pka(cs0, x0); cs1 = pka(cs1, x1);
            }
        }
        const float C25 = 1.f / 25.f;
        float* o0 = po + (size_t)(oy + r0) * 1024 + ox + c0v;
        *(float4*)o0 = make_float4(cs0.x*C25, cs0.y*C25, cs1.x*C25, cs1.y*C25);
        {
            uint2 v = *(const uint2*)(hp + 5 * ST);
            cs0 = pka(pka(cs0, up2(v.x)), -a00); cs1 = pka(pka(cs1, up2(v.y)), -a01);
        }
        *(float4*)(o0 + 1024) = make_float4(cs0.x*C25, cs0.y*C25, cs1.x*C25, cs1.y*C25);
        {
            uint2 v = *(const uint2*)(hp + 6 * ST);
            cs0 = pka(pka(cs0, up2(v.x)), -a10); cs1 = pka(pka(cs1, up2(v.y)), -a11);
        }
        *(float4*)(o0 + 2048) = make_float4(cs0.x*C25, cs0.y*C25, cs1.x*C25, cs1.y*C25);
        {
            uint2 v = *(const uint2*)(hp + 7 * ST);
            cs0 = pka(pka(cs0, up2(v.x)), -a20); cs1 = pka(pka(cs1, up2(v.y)), -a21);
        }
        *(float4*)(o0 + 3072) = make_float4(cs0.x*C25, cs0.y*C25, cs1.x*C25, cs1.y*C25);
    }
}

__global__ __launch_bounds__(BLOCK, 4)
void wrd_kernel(const float* __restrict__ img, float* __restrict__ out) {
    __shared__ u16 sLum[96 * SL + 16];  // 20000 B
    __shared__ u16 sBT [96 * SL];       // 19968 B
    __shared__ u16 sT1 [96 * ST];       // 19968 B
    __shared__ u16 sDC [96 * SD];       // 16896 B

    int bid = blockIdx.x, nwg = gridDim.x;
    int flat = ((nwg & 7) == 0) ? ((bid & 7) * (nwg >> 3) + (bid >> 3)) : bid;
    const int b = flat >> 8;
    const int t = flat & 255;
    const int oy = (t >> 4) * 64, ox = (t & 15) * 64;

    const float* pR = img + (size_t)b * 3145728u;
    const float* pG = pR + 1048576;
    const float* pB = pR + 2097152;
    float* po = out + (size_t)b * 1048576u;

    bool edge = (ox == 0) | (oy == 0) | (ox == 960) | (oy == 960);
    if (edge) body<true >(pR, pG, pB, po, oy, ox, threadIdx.x, sLum, sBT, sT1, sDC);
    else      body<false>(pR, pG, pB, po, oy, ox, threadIdx.x, sLum, sBT, sT1, sDC);
}

extern "C" void kernel_launch(void* const* d_in, const int* in_sizes, int n_in,
                              void* d_out, int out_size, void* d_ws, size_t ws_size,
                              hipStream_t stream) {
    const float* img = (const float*)d_in[0];
    float* out = (float*)d_out;
    int Bn = in_sizes[0] / (3 * 1024 * 1024);
    int nwg = Bn * 256;
    hipLaunchKernelGGL(wrd_kernel, dim3(nwg), dim3(BLOCK), 0, stream, img, out);
}

// Round 11
// 117.240 us; speedup vs baseline: 1.2591x; 1.2591x over previous
//
#include <hip/hip_runtime.h>

// Round 11: r4 base (proven 113.8us) + two proven deltas:
//  (1) P5: brightness-mask lum computed f32 from the rgb already loaded for
//      saturation (exact reference semantics; proven in r2). Drops 2 LDS
//      reads + 4 unpacks per emit.
//  (2) P6b: r6's 2-row x 16-quad variant (512 tasks = 100% util; passed r6).
// All else r4-verbatim. LDS 51296 B -> 3 blocks/CU.
// Semantics: box15 zero-padded /225 always; d, comb forced 0 outside image;
// avgpool5 count_include_pad /25 always.

#define BLOCK 512
typedef unsigned short u16;
typedef unsigned int u32;
typedef __attribute__((ext_vector_type(2))) float f32x2;

#define SL 104   // sLum u16 stride (208 B)
#define S1 88    // sT1 / sDC u16 stride (176 B)

__device__ __forceinline__ float blo(u32 u){ return __uint_as_float(u << 16); }
__device__ __forceinline__ float bhi(u32 u){ return __uint_as_float(u & 0xffff0000u); }
__device__ __forceinline__ float bf2f(u16 h){ return __uint_as_float(((u32)h) << 16); }
__device__ __forceinline__ u32 pk2(float lo, float hi){
    u32 r; asm("v_cvt_pk_bf16_f32 %0, %1, %2" : "=v"(r) : "v"(lo), "v"(hi)); return r;
}
__device__ __forceinline__ f32x2 pka(f32x2 a, f32x2 b){
    f32x2 d; asm("v_pk_add_f32 %0, %1, %2" : "=v"(d) : "v"(a), "v"(b)); return d;
}
__device__ __forceinline__ f32x2 up2(u32 u){
    f32x2 r; r.x = __uint_as_float(u << 16); r.y = __uint_as_float(u & 0xffff0000u); return r;
}
__device__ __forceinline__ float sigf(float x){ return 1.f / (1.f + __expf(-x)); }
__device__ __forceinline__ float clamp01(float x){ return fminf(fmaxf(x, 0.f), 1.f); }
__device__ __forceinline__ void unp8(uint4 v, float* o){
    o[0]=blo(v.x); o[1]=bhi(v.x); o[2]=blo(v.y); o[3]=bhi(v.y);
    o[4]=blo(v.z); o[5]=bhi(v.z); o[6]=blo(v.w); o[7]=bhi(v.w);
}
__device__ __forceinline__ float satm(float r_, float g_, float b_){
    float mx = fmaxf(r_, fmaxf(g_, b_));
    float mn = fminf(r_, fminf(g_, b_));
    float sat = (mx - mn) / (mx + 1e-8f);
    return sigf((0.3f - sat) * 10.f);
}
__device__ __forceinline__ float lumf(float r_, float g_, float b_){
    return fmaf(0.299f, r_, fmaf(0.587f, g_, 0.114f * b_));
}

template<bool EDGE>
__device__ __forceinline__ void body(const float* __restrict__ pR,
                                     const float* __restrict__ pG,
                                     const float* __restrict__ pB,
                                     float* __restrict__ po,
                                     int oy, int ox, int tid,
                                     u16* sLum, u16* sT1, u16* sDC)
{
    const float C225 = 1.f / 225.f;
    const float CF   = 50.f / 225.f;

    // ---- P1: lum bf16, 96 rows x 6 groups of 16 cols (r4 verbatim) ----
    for (int task = tid; task < 96 * 6; task += BLOCK) {
        int r = task / 6, c = task - r * 6;
        int gy = oy - 16 + r;
        int gxb = ox - 16 + 16 * c;
        u32 pk[8];
        #pragma unroll
        for (int sq = 0; sq < 4; ++sq) {
            int gx = gxb + 4 * sq;
            float l0 = 0.f, l1 = 0.f, l2 = 0.f, l3 = 0.f;
            if (!EDGE || ((unsigned)gy < 1024u && (unsigned)gx < 1024u)) {
                int idx = gy * 1024 + gx;
                float4 R  = *(const float4*)&pR[idx];
                float4 G  = *(const float4*)&pG[idx];
                float4 Bc = *(const float4*)&pB[idx];
                l0 = lumf(R.x, G.x, Bc.x);
                l1 = lumf(R.y, G.y, Bc.y);
                l2 = lumf(R.z, G.z, Bc.z);
                l3 = lumf(R.w, G.w, Bc.w);
            }
            pk[2 * sq]     = pk2(l0, l1);
            pk[2 * sq + 1] = pk2(l2, l3);
        }
        u16* dst = &sLum[r * SL + 16 * c];
        *(uint4*)dst     = make_uint4(pk[0], pk[1], pk[2], pk[3]);
        *(uint4*)(dst+8) = make_uint4(pk[4], pk[5], pk[6], pk[7]);
    }
    __syncthreads();

    // ---- P2: hbox15(lum) -> sT1 bf16; 96 rows x 7 groups of 12 (r4) ----
    for (int task = tid; task < 96 * 7; task += BLOCK) {
        int r = task / 7, g = task - r * 7;
        int s0 = 12 * g, c0 = s0 & ~7;
        const u16* lr = &sLum[r * SL + c0];
        float lv[32];
        unp8(*(const uint4*)lr,        lv);
        unp8(*(const uint4*)(lr + 8),  lv + 8);
        unp8(*(const uint4*)(lr + 16), lv + 16);
        unp8(*(const uint4*)(lr + 24), lv + 24);
        if (s0 & 4) {
            #pragma unroll
            for (int i = 0; i < 28; ++i) lv[i] = lv[i + 4];
        }
        float o[12];
        float s = 0.f;
        #pragma unroll
        for (int k = 0; k < 15; ++k) s += lv[k];
        o[0] = s;
        #pragma unroll
        for (int j = 1; j < 12; ++j) { s += lv[j + 14] - lv[j - 1]; o[j] = s; }
        u16* dst = &sT1[r * S1 + s0];
        *(uint2*)dst       = make_uint2(pk2(o[0], o[1]),  pk2(o[2], o[3]));
        *(uint2*)(dst + 4) = make_uint2(pk2(o[4], o[5]),  pk2(o[6], o[7]));
        *(uint2*)(dst + 8) = make_uint2(pk2(o[8], o[9]),  pk2(o[10], o[11]));
    }
    __syncthreads();

    // ---- P3: mean = vbox15/225; d=(lum-mean)^2 bf16 -> sDC (r4) ----
    for (int task = tid; task < 21 * 21; task += BLOCK) {
        int rg = task / 21, q = task - rg * 21;
        int r0 = 4 * rg;
        const u16* hp = &sT1[r0 * S1 + 4 * q];
        float cs0 = 0.f, cs1 = 0.f, cs2 = 0.f, cs3 = 0.f;
        float a00, a01, a02, a03, a10, a11, a12, a13, a20, a21, a22, a23;
        #pragma unroll
        for (int k = 0; k < 15; ++k) {
            uint2 v = *(const uint2*)(hp + k * S1);
            float x0 = blo(v.x), x1 = bhi(v.x), x2 = blo(v.y), x3 = bhi(v.y);
            if (k == 0) { a00 = x0; a01 = x1; a02 = x2; a03 = x3; }
            if (k == 1) { a10 = x0; a11 = x1; a12 = x2; a13 = x3; }
            if (k == 2) { a20 = x0; a21 = x1; a22 = x2; a23 = x3; }
            cs0 += x0; cs1 += x1; cs2 += x2; cs3 += x3;
        }
        auto emitD = [&](int row) {
            float m0 = cs0 * C225, m1 = cs1 * C225, m2 = cs2 * C225, m3 = cs3 * C225;
            const u16* lp = &sLum[(row + 7) * SL + 4 * q + 4];
            ushort4 A  = *(const ushort4*)lp;
            ushort4 Bv = *(const ushort4*)(lp + 4);
            float t0 = bf2f(A.w)  - m0, t1 = bf2f(Bv.x) - m1;
            float t2 = bf2f(Bv.y) - m2, t3 = bf2f(Bv.z) - m3;
            float d0 = t0 * t0, d1 = t1 * t1, d2 = t2 * t2, d3 = t3 * t3;
            if (EDGE) {
                int gy = oy - 9 + row, gx = ox - 9 + 4 * q;
                bool vy = (unsigned)gy < 1024u;
                d0 = (vy && (unsigned)(gx    ) < 1024u) ? d0 : 0.f;
                d1 = (vy && (unsigned)(gx + 1) < 1024u) ? d1 : 0.f;
                d2 = (vy && (unsigned)(gx + 2) < 1024u) ? d2 : 0.f;
                d3 = (vy && (unsigned)(gx + 3) < 1024u) ? d3 : 0.f;
            }
            *(uint2*)&sDC[row * S1 + 4 * q] = make_uint2(pk2(d0, d1), pk2(d2, d3));
        };
        emitD(r0);
        {
            uint2 v = *(const uint2*)(hp + 15 * S1);
            cs0 += blo(v.x) - a00; cs1 += bhi(v.x) - a01;
            cs2 += blo(v.y) - a02; cs3 += bhi(v.y) - a03;
        }
        emitD(r0 + 1);
        if (r0 + 2 < 82) {
            uint2 v = *(const uint2*)(hp + 16 * S1);
            cs0 += blo(v.x) - a10; cs1 += bhi(v.x) - a11;
            cs2 += blo(v.y) - a12; cs3 += bhi(v.y) - a13;
            emitD(r0 + 2);
            uint2 w = *(const uint2*)(hp + 17 * S1);
            cs0 += blo(w.x) - a20; cs1 += bhi(w.x) - a21;
            cs2 += blo(w.y) - a22; cs3 += bhi(w.y) - a23;
            emitD(r0 + 3);
        }
    }
    __syncthreads();

    // ---- P4: hbox15(d) -> sT1 bf16; 82 rows x 6 groups of 12 (r4) ----
    for (int task = tid; task < 82 * 6; task += BLOCK) {
        int r = task / 6, g = task - r * 6;
        int s0 = 12 * g, c0 = s0 & ~7;
        const u16* dr = &sDC[r * S1 + c0];
        float lv[32];
        unp8(*(const uint4*)dr,        lv);
        unp8(*(const uint4*)(dr + 8),  lv + 8);
        unp8(*(const uint4*)(dr + 16), lv + 16);
        unp8(*(const uint4*)(dr + 24), lv + 24);
        if (s0 & 4) {
            #pragma unroll
            for (int i = 0; i < 28; ++i) lv[i] = lv[i + 4];
        }
        float o[12];
        float s = 0.f;
        #pragma unroll
        for (int k = 0; k < 15; ++k) s += lv[k];
        o[0] = s;
        #pragma unroll
        for (int j = 1; j < 12; ++j) { s += lv[j + 14] - lv[j - 1]; o[j] = s; }
        u16* dst = &sT1[r * S1 + s0];
        *(uint2*)dst       = make_uint2(pk2(o[0], o[1]),  pk2(o[2], o[3]));
        *(uint2*)(dst + 4) = make_uint2(pk2(o[4], o[5]),  pk2(o[6], o[7]));
        *(uint2*)(dst + 8) = make_uint2(pk2(o[8], o[9]),  pk2(o[10], o[11]));
    }
    __syncthreads();

    // ---- P5: var via vbox15; comb bf16 -> sDC; lum for bm from rgb (f32) ----
    for (int task = tid; task < 17 * 17; task += BLOCK) {
        int rg = task / 17, q = task - rg * 17;
        int r0 = 4 * rg;
        const u16* hp = &sT1[r0 * S1 + 4 * q];
        float cs0 = 0.f, cs1 = 0.f, cs2 = 0.f, cs3 = 0.f;
        float a00, a01, a02, a03, a10, a11, a12, a13, a20, a21, a22, a23;
        #pragma unroll
        for (int k = 0; k < 15; ++k) {
            uint2 v = *(const uint2*)(hp + k * S1);
            float x0 = blo(v.x), x1 = bhi(v.x), x2 = blo(v.y), x3 = bhi(v.y);
            if (k == 0) { a00 = x0; a01 = x1; a02 = x2; a03 = x3; }
            if (k == 1) { a10 = x0; a11 = x1; a12 = x2; a13 = x3; }
            if (k == 2) { a20 = x0; a21 = x1; a22 = x2; a23 = x3; }
            cs0 += x0; cs1 += x1; cs2 += x2; cs3 += x3;
        }
        auto emitC = [&](int row) {
            float cm0 = sigf(fmaf(cs0, CF, -0.5f));
            float cm1 = sigf(fmaf(cs1, CF, -0.5f));
            float cm2 = sigf(fmaf(cs2, CF, -0.5f));
            float cm3 = sigf(fmaf(cs3, CF, -0.5f));
            int gy = oy - 2 + row, gx0 = ox - 2 + 4 * q;
            int i0 = gy * 1024 + gx0;
            float2 z2 = make_float2(0.f, 0.f);
            float2 Ra, Rb, Ga, Gb, Ba, Bb;
            bool va = true, vb = true;
            if (EDGE) {
                bool vy = (unsigned)gy < 1024u;
                va = vy && (unsigned)gx0 < 1024u;
                vb = vy && (unsigned)(gx0 + 2) < 1024u;
                Ra = va ? *(const float2*)&pR[i0]     : z2;
                Rb = vb ? *(const float2*)&pR[i0 + 2] : z2;
                Ga = va ? *(const float2*)&pG[i0]     : z2;
                Gb = vb ? *(const float2*)&pG[i0 + 2] : z2;
                Ba = va ? *(const float2*)&pB[i0]     : z2;
                Bb = vb ? *(const float2*)&pB[i0 + 2] : z2;
            } else {
                Ra = *(const float2*)&pR[i0];  Rb = *(const float2*)&pR[i0 + 2];
                Ga = *(const float2*)&pG[i0];  Gb = *(const float2*)&pG[i0 + 2];
                Ba = *(const float2*)&pB[i0];  Bb = *(const float2*)&pB[i0 + 2];
            }
            float bm0 = sigf((lumf(Ra.x, Ga.x, Ba.x) - 0.7f) * 10.f);
            float bm1 = sigf((lumf(Ra.y, Ga.y, Ba.y) - 0.7f) * 10.f);
            float bm2 = sigf((lumf(Rb.x, Gb.x, Bb.x) - 0.7f) * 10.f);
            float bm3 = sigf((lumf(Rb.y, Gb.y, Bb.y) - 0.7f) * 10.f);
            float cb0 = clamp01(bm0 + 0.5f * cm0 * satm(Ra.x, Ga.x, Ba.x));
            float cb1 = clamp01(bm1 + 0.5f * cm1 * satm(Ra.y, Ga.y, Ba.y));
            float cb2 = clamp01(bm2 + 0.5f * cm2 * satm(Rb.x, Gb.x, Bb.x));
            float cb3 = clamp01(bm3 + 0.5f * cm3 * satm(Rb.y, Gb.y, Bb.y));
            if (EDGE) {
                cb0 = va ? cb0 : 0.f;  cb1 = va ? cb1 : 0.f;
                cb2 = vb ? cb2 : 0.f;  cb3 = vb ? cb3 : 0.f;
            }
            *(uint2*)&sDC[row * S1 + 4 * q] = make_uint2(pk2(cb0, cb1), pk2(cb2, cb3));
        };
        emitC(r0);
        {
            uint2 v = *(const uint2*)(hp + 15 * S1);
            cs0 += blo(v.x) - a00; cs1 += bhi(v.x) - a01;
            cs2 += blo(v.y) - a02; cs3 += bhi(v.y) - a03;
        }
        emitC(r0 + 1);
        {
            uint2 v = *(const uint2*)(hp + 16 * S1);
            cs0 += blo(v.x) - a10; cs1 += bhi(v.x) - a11;
            cs2 += blo(v.y) - a12; cs3 += bhi(v.y) - a13;
        }
        emitC(r0 + 2);
        {
            uint2 v = *(const uint2*)(hp + 17 * S1);
            cs0 += blo(v.x) - a20; cs1 += bhi(v.x) - a21;
            cs2 += blo(v.y) - a22; cs3 += bhi(v.y) - a23;
        }
        emitC(r0 + 3);
    }
    __syncthreads();

    // ---- P6a: hpool5(comb) -> sT1 bf16; 68 rows x 4 groups of 16 (r4) ----
    for (int task = tid; task < 68 * 4; task += BLOCK) {
        int r = task >> 2, g = task & 3;
        int s0 = 16 * g;
        const u16* cr = &sDC[r * S1 + s0];
        float cv[24];
        unp8(*(const uint4*)cr,        cv);
        unp8(*(const uint4*)(cr + 8),  cv + 8);
        unp8(*(const uint4*)(cr + 16), cv + 16);
        float o[16];
        float s = cv[0] + cv[1] + cv[2] + cv[3] + cv[4];
        o[0] = s;
        #pragma unroll
        for (int j = 1; j < 16; ++j) { s += cv[j + 4] - cv[j - 1]; o[j] = s; }
        u16* dst = &sT1[r * S1 + s0];
        *(uint4*)dst = make_uint4(pk2(o[0], o[1]), pk2(o[2], o[3]),
                                  pk2(o[4], o[5]), pk2(o[6], o[7]));
        *(uint4*)(dst + 8) = make_uint4(pk2(o[8],  o[9]),  pk2(o[10], o[11]),
                                        pk2(o[12], o[13]), pk2(o[14], o[15]));
    }
    __syncthreads();

    // ---- P6b: vpool5 -> out; 32 row-groups of 2 x 16 col-quads (512, r6) ----
    for (int task = tid; task < 512; task += BLOCK) {
        int rg = task >> 4, q = task & 15;
        int r0 = 2 * rg, c0 = 4 * q;
        const u16* hp = &sT1[r0 * S1 + c0];
        f32x2 a0, a1, cs0, cs1;
        {
            uint2 v = *(const uint2*)hp;
            a0 = up2(v.x); a1 = up2(v.y);
        }
        {
            uint2 v = *(const uint2*)(hp + S1);
            cs0 = up2(v.x); cs1 = up2(v.y);
        }
        {
            uint2 v = *(const uint2*)(hp + 2 * S1);
            cs0 = pka(cs0, up2(v.x)); cs1 = pka(cs1, up2(v.y));
        }
        {
            uint2 v = *(const uint2*)(hp + 3 * S1);
            cs0 = pka(cs0, up2(v.x)); cs1 = pka(cs1, up2(v.y));
        }
        {
            uint2 v = *(const uint2*)(hp + 4 * S1);
            cs0 = pka(cs0, up2(v.x)); cs1 = pka(cs1, up2(v.y));
        }
        const float C25 = 1.f / 25.f;
        float* o0 = po + (size_t)(oy + r0) * 1024 + ox + c0;
        f32x2 t0 = pka(cs0, a0), t1 = pka(cs1, a1);
        *(float4*)o0 = make_float4(t0.x*C25, t0.y*C25, t1.x*C25, t1.y*C25);
        {
            uint2 v = *(const uint2*)(hp + 5 * S1);
            t0 = pka(cs0, up2(v.x)); t1 = pka(cs1, up2(v.y));
        }
        *(float4*)(o0 + 1024) = make_float4(t0.x*C25, t0.y*C25, t1.x*C25, t1.y*C25);
    }
}

__global__ __launch_bounds__(BLOCK, 6)
void wrd_kernel(const float* __restrict__ img, float* __restrict__ out) {
    __shared__ u16 sLum[96 * SL];   // 19968 B
    __shared__ u16 sT1[96 * S1];    // 16896 B
    __shared__ u16 sDC[82 * S1];    // 14432 B  (d, then comb)

    int bid = blockIdx.x, nwg = gridDim.x;
    int flat = ((nwg & 7) == 0) ? ((bid & 7) * (nwg >> 3) + (bid >> 3)) : bid;
    const int b = flat >> 8;
    const int t = flat & 255;
    const int oy = (t >> 4) * 64, ox = (t & 15) * 64;

    const float* pR = img + (size_t)b * 3145728u;
    const float* pG = pR + 1048576;
    const float* pB = pR + 2097152;
    float* po = out + (size_t)b * 1048576u;

    bool edge = (ox == 0) | (oy == 0) | (ox == 960) | (oy == 960);
    if (edge) body<true >(pR, pG, pB, po, oy, ox, threadIdx.x, sLum, sT1, sDC);
    else      body<false>(pR, pG, pB, po, oy, ox, threadIdx.x, sLum, sT1, sDC);
}

extern "C" void kernel_launch(void* const* d_in, const int* in_sizes, int n_in,
                              void* d_out, int out_size, void* d_ws, size_t ws_size,
                              hipStream_t stream) {
    const float* img = (const float*)d_in[0];
    float* out = (float*)d_out;
    int Bn = in_sizes[0] / (3 * 1024 * 1024);
    int nwg = Bn * 256;
    hipLaunchKernelGGL(wrd_kernel, dim3(nwg), dim3(BLOCK), 0, stream, img, out);
}

// Round 12
// 116.853 us; speedup vs baseline: 1.2633x; 1.0033x over previous
//
#include <hip/hip_runtime.h>

// Round 12: r4 verbatim + ONLY the P5-lum-from-rgb delta (isolated positive
// component of r11; r11's P6b-2row delta identified as the regression and
// reverted to r4's 4-row P6b).
// LDS 51296 B -> 3 blocks/CU.
// Semantics: box15 zero-padded /225 always; d, comb forced 0 outside image;
// avgpool5 count_include_pad /25 always.

#define BLOCK 512
typedef unsigned short u16;
typedef unsigned int u32;

#define SL 104   // sLum u16 stride (208 B)
#define S1 88    // sT1 / sDC u16 stride (176 B)

__device__ __forceinline__ float blo(u32 u){ return __uint_as_float(u << 16); }
__device__ __forceinline__ float bhi(u32 u){ return __uint_as_float(u & 0xffff0000u); }
__device__ __forceinline__ float bf2f(u16 h){ return __uint_as_float(((u32)h) << 16); }
__device__ __forceinline__ u32 pk2(float lo, float hi){
    u32 r; asm("v_cvt_pk_bf16_f32 %0, %1, %2" : "=v"(r) : "v"(lo), "v"(hi)); return r;
}
__device__ __forceinline__ float sigf(float x){ return 1.f / (1.f + __expf(-x)); }
__device__ __forceinline__ float clamp01(float x){ return fminf(fmaxf(x, 0.f), 1.f); }
__device__ __forceinline__ void unp8(uint4 v, float* o){
    o[0]=blo(v.x); o[1]=bhi(v.x); o[2]=blo(v.y); o[3]=bhi(v.y);
    o[4]=blo(v.z); o[5]=bhi(v.z); o[6]=blo(v.w); o[7]=bhi(v.w);
}
__device__ __forceinline__ float satm(float r_, float g_, float b_){
    float mx = fmaxf(r_, fmaxf(g_, b_));
    float mn = fminf(r_, fminf(g_, b_));
    float sat = (mx - mn) / (mx + 1e-8f);
    return sigf((0.3f - sat) * 10.f);
}
__device__ __forceinline__ float lumf(float r_, float g_, float b_){
    return fmaf(0.299f, r_, fmaf(0.587f, g_, 0.114f * b_));
}

template<bool EDGE>
__device__ __forceinline__ void body(const float* __restrict__ pR,
                                     const float* __restrict__ pG,
                                     const float* __restrict__ pB,
                                     float* __restrict__ po,
                                     int oy, int ox, int tid,
                                     u16* sLum, u16* sT1, u16* sDC)
{
    const float C225 = 1.f / 225.f;
    const float CF   = 50.f / 225.f;

    // ---- P1: lum bf16, 96 rows x 6 groups of 16 cols ----
    for (int task = tid; task < 96 * 6; task += BLOCK) {
        int r = task / 6, c = task - r * 6;
        int gy = oy - 16 + r;
        int gxb = ox - 16 + 16 * c;
        u32 pk[8];
        #pragma unroll
        for (int sq = 0; sq < 4; ++sq) {
            int gx = gxb + 4 * sq;
            float l0 = 0.f, l1 = 0.f, l2 = 0.f, l3 = 0.f;
            if (!EDGE || ((unsigned)gy < 1024u && (unsigned)gx < 1024u)) {
                int idx = gy * 1024 + gx;
                float4 R  = *(const float4*)&pR[idx];
                float4 G  = *(const float4*)&pG[idx];
                float4 Bc = *(const float4*)&pB[idx];
                l0 = lumf(R.x, G.x, Bc.x);
                l1 = lumf(R.y, G.y, Bc.y);
                l2 = lumf(R.z, G.z, Bc.z);
                l3 = lumf(R.w, G.w, Bc.w);
            }
            pk[2 * sq]     = pk2(l0, l1);
            pk[2 * sq + 1] = pk2(l2, l3);
        }
        u16* dst = &sLum[r * SL + 16 * c];
        *(uint4*)dst     = make_uint4(pk[0], pk[1], pk[2], pk[3]);
        *(uint4*)(dst+8) = make_uint4(pk[4], pk[5], pk[6], pk[7]);
    }
    __syncthreads();

    // ---- P2: hbox15(lum) -> sT1 bf16; 96 rows x 7 groups of 12 ----
    for (int task = tid; task < 96 * 7; task += BLOCK) {
        int r = task / 7, g = task - r * 7;
        int s0 = 12 * g, c0 = s0 & ~7;
        const u16* lr = &sLum[r * SL + c0];
        float lv[32];
        unp8(*(const uint4*)lr,        lv);
        unp8(*(const uint4*)(lr + 8),  lv + 8);
        unp8(*(const uint4*)(lr + 16), lv + 16);
        unp8(*(const uint4*)(lr + 24), lv + 24);
        if (s0 & 4) {
            #pragma unroll
            for (int i = 0; i < 28; ++i) lv[i] = lv[i + 4];
        }
        float o[12];
        float s = 0.f;
        #pragma unroll
        for (int k = 0; k < 15; ++k) s += lv[k];
        o[0] = s;
        #pragma unroll
        for (int j = 1; j < 12; ++j) { s += lv[j + 14] - lv[j - 1]; o[j] = s; }
        u16* dst = &sT1[r * S1 + s0];
        *(uint2*)dst       = make_uint2(pk2(o[0], o[1]),  pk2(o[2], o[3]));
        *(uint2*)(dst + 4) = make_uint2(pk2(o[4], o[5]),  pk2(o[6], o[7]));
        *(uint2*)(dst + 8) = make_uint2(pk2(o[8], o[9]),  pk2(o[10], o[11]));
    }
    __syncthreads();

    // ---- P3: mean = vbox15/225; d=(lum-mean)^2 bf16 -> sDC ----
    for (int task = tid; task < 21 * 21; task += BLOCK) {
        int rg = task / 21, q = task - rg * 21;
        int r0 = 4 * rg;
        const u16* hp = &sT1[r0 * S1 + 4 * q];
        float cs0 = 0.f, cs1 = 0.f, cs2 = 0.f, cs3 = 0.f;
        float a00, a01, a02, a03, a10, a11, a12, a13, a20, a21, a22, a23;
        #pragma unroll
        for (int k = 0; k < 15; ++k) {
            uint2 v = *(const uint2*)(hp + k * S1);
            float x0 = blo(v.x), x1 = bhi(v.x), x2 = blo(v.y), x3 = bhi(v.y);
            if (k == 0) { a00 = x0; a01 = x1; a02 = x2; a03 = x3; }
            if (k == 1) { a10 = x0; a11 = x1; a12 = x2; a13 = x3; }
            if (k == 2) { a20 = x0; a21 = x1; a22 = x2; a23 = x3; }
            cs0 += x0; cs1 += x1; cs2 += x2; cs3 += x3;
        }
        auto emitD = [&](int row) {
            float m0 = cs0 * C225, m1 = cs1 * C225, m2 = cs2 * C225, m3 = cs3 * C225;
            const u16* lp = &sLum[(row + 7) * SL + 4 * q + 4];
            ushort4 A  = *(const ushort4*)lp;
            ushort4 Bv = *(const ushort4*)(lp + 4);
            float t0 = bf2f(A.w)  - m0, t1 = bf2f(Bv.x) - m1;
            float t2 = bf2f(Bv.y) - m2, t3 = bf2f(Bv.z) - m3;
            float d0 = t0 * t0, d1 = t1 * t1, d2 = t2 * t2, d3 = t3 * t3;
            if (EDGE) {
                int gy = oy - 9 + row, gx = ox - 9 + 4 * q;
                bool vy = (unsigned)gy < 1024u;
                d0 = (vy && (unsigned)(gx    ) < 1024u) ? d0 : 0.f;
                d1 = (vy && (unsigned)(gx + 1) < 1024u) ? d1 : 0.f;
                d2 = (vy && (unsigned)(gx + 2) < 1024u) ? d2 : 0.f;
                d3 = (vy && (unsigned)(gx + 3) < 1024u) ? d3 : 0.f;
            }
            *(uint2*)&sDC[row * S1 + 4 * q] = make_uint2(pk2(d0, d1), pk2(d2, d3));
        };
        emitD(r0);
        {
            uint2 v = *(const uint2*)(hp + 15 * S1);
            cs0 += blo(v.x) - a00; cs1 += bhi(v.x) - a01;
            cs2 += blo(v.y) - a02; cs3 += bhi(v.y) - a03;
        }
        emitD(r0 + 1);
        if (r0 + 2 < 82) {
            uint2 v = *(const uint2*)(hp + 16 * S1);
            cs0 += blo(v.x) - a10; cs1 += bhi(v.x) - a11;
            cs2 += blo(v.y) - a12; cs3 += bhi(v.y) - a13;
            emitD(r0 + 2);
            uint2 w = *(const uint2*)(hp + 17 * S1);
            cs0 += blo(w.x) - a20; cs1 += bhi(w.x) - a21;
            cs2 += blo(w.y) - a22; cs3 += bhi(w.y) - a23;
            emitD(r0 + 3);
        }
    }
    __syncthreads();

    // ---- P4: hbox15(d) -> sT1 bf16; 82 rows x 6 groups of 12 ----
    for (int task = tid; task < 82 * 6; task += BLOCK) {
        int r = task / 6, g = task - r * 6;
        int s0 = 12 * g, c0 = s0 & ~7;
        const u16* dr = &sDC[r * S1 + c0];
        float lv[32];
        unp8(*(const uint4*)dr,        lv);
        unp8(*(const uint4*)(dr + 8),  lv + 8);
        unp8(*(const uint4*)(dr + 16), lv + 16);
        unp8(*(const uint4*)(dr + 24), lv + 24);
        if (s0 & 4) {
            #pragma unroll
            for (int i = 0; i < 28; ++i) lv[i] = lv[i + 4];
        }
        float o[12];
        float s = 0.f;
        #pragma unroll
        for (int k = 0; k < 15; ++k) s += lv[k];
        o[0] = s;
        #pragma unroll
        for (int j = 1; j < 12; ++j) { s += lv[j + 14] - lv[j - 1]; o[j] = s; }
        u16* dst = &sT1[r * S1 + s0];
        *(uint2*)dst       = make_uint2(pk2(o[0], o[1]),  pk2(o[2], o[3]));
        *(uint2*)(dst + 4) = make_uint2(pk2(o[4], o[5]),  pk2(o[6], o[7]));
        *(uint2*)(dst + 8) = make_uint2(pk2(o[8], o[9]),  pk2(o[10], o[11]));
    }
    __syncthreads();

    // ---- P5: var via vbox15; comb bf16 -> sDC; bm-lum from rgb (f32 exact) ----
    for (int task = tid; task < 17 * 17; task += BLOCK) {
        int rg = task / 17, q = task - rg * 17;
        int r0 = 4 * rg;
        const u16* hp = &sT1[r0 * S1 + 4 * q];
        float cs0 = 0.f, cs1 = 0.f, cs2 = 0.f, cs3 = 0.f;
        float a00, a01, a02, a03, a10, a11, a12, a13, a20, a21, a22, a23;
        #pragma unroll
        for (int k = 0; k < 15; ++k) {
            uint2 v = *(const uint2*)(hp + k * S1);
            float x0 = blo(v.x), x1 = bhi(v.x), x2 = blo(v.y), x3 = bhi(v.y);
            if (k == 0) { a00 = x0; a01 = x1; a02 = x2; a03 = x3; }
            if (k == 1) { a10 = x0; a11 = x1; a12 = x2; a13 = x3; }
            if (k == 2) { a20 = x0; a21 = x1; a22 = x2; a23 = x3; }
            cs0 += x0; cs1 += x1; cs2 += x2; cs3 += x3;
        }
        auto emitC = [&](int row) {
            float cm0 = sigf(fmaf(cs0, CF, -0.5f));
            float cm1 = sigf(fmaf(cs1, CF, -0.5f));
            float cm2 = sigf(fmaf(cs2, CF, -0.5f));
            float cm3 = sigf(fmaf(cs3, CF, -0.5f));
            int gy = oy - 2 + row, gx0 = ox - 2 + 4 * q;
            int i0 = gy * 1024 + gx0;
            float2 z2 = make_float2(0.f, 0.f);
            float2 Ra, Rb, Ga, Gb, Ba, Bb;
            bool va = true, vb = true;
            if (EDGE) {
                bool vy = (unsigned)gy < 1024u;
                va = vy && (unsigned)gx0 < 1024u;
                vb = vy && (unsigned)(gx0 + 2) < 1024u;
                Ra = va ? *(const float2*)&pR[i0]     : z2;
                Rb = vb ? *(const float2*)&pR[i0 + 2] : z2;
                Ga = va ? *(const float2*)&pG[i0]     : z2;
                Gb = vb ? *(const float2*)&pG[i0 + 2] : z2;
                Ba = va ? *(const float2*)&pB[i0]     : z2;
                Bb = vb ? *(const float2*)&pB[i0 + 2] : z2;
            } else {
                Ra = *(const float2*)&pR[i0];  Rb = *(const float2*)&pR[i0 + 2];
                Ga = *(const float2*)&pG[i0];  Gb = *(const float2*)&pG[i0 + 2];
                Ba = *(const float2*)&pB[i0];  Bb = *(const float2*)&pB[i0 + 2];
            }
            float bm0 = sigf((lumf(Ra.x, Ga.x, Ba.x) - 0.7f) * 10.f);
            float bm1 = sigf((lumf(Ra.y, Ga.y, Ba.y) - 0.7f) * 10.f);
            float bm2 = sigf((lumf(Rb.x, Gb.x, Bb.x) - 0.7f) * 10.f);
            float bm3 = sigf((lumf(Rb.y, Gb.y, Bb.y) - 0.7f) * 10.f);
            float cb0 = clamp01(bm0 + 0.5f * cm0 * satm(Ra.x, Ga.x, Ba.x));
            float cb1 = clamp01(bm1 + 0.5f * cm1 * satm(Ra.y, Ga.y, Ba.y));
            float cb2 = clamp01(bm2 + 0.5f * cm2 * satm(Rb.x, Gb.x, Bb.x));
            float cb3 = clamp01(bm3 + 0.5f * cm3 * satm(Rb.y, Gb.y, Bb.y));
            if (EDGE) {
                cb0 = va ? cb0 : 0.f;  cb1 = va ? cb1 : 0.f;
                cb2 = vb ? cb2 : 0.f;  cb3 = vb ? cb3 : 0.f;
            }
            *(uint2*)&sDC[row * S1 + 4 * q] = make_uint2(pk2(cb0, cb1), pk2(cb2, cb3));
        };
        emitC(r0);
        {
            uint2 v = *(const uint2*)(hp + 15 * S1);
            cs0 += blo(v.x) - a00; cs1 += bhi(v.x) - a01;
            cs2 += blo(v.y) - a02; cs3 += bhi(v.y) - a03;
        }
        emitC(r0 + 1);
        {
            uint2 v = *(const uint2*)(hp + 16 * S1);
            cs0 += blo(v.x) - a10; cs1 += bhi(v.x) - a11;
            cs2 += blo(v.y) - a12; cs3 += bhi(v.y) - a13;
        }
        emitC(r0 + 2);
        {
            uint2 v = *(const uint2*)(hp + 17 * S1);
            cs0 += blo(v.x) - a20; cs1 += bhi(v.x) - a21;
            cs2 += blo(v.y) - a22; cs3 += bhi(v.y) - a23;
        }
        emitC(r0 + 3);
    }
    __syncthreads();

    // ---- P6a: hpool5(comb) -> sT1 bf16; 68 rows x 4 groups of 16 ----
    for (int task = tid; task < 68 * 4; task += BLOCK) {
        int r = task >> 2, g = task & 3;
        int s0 = 16 * g;
        const u16* cr = &sDC[r * S1 + s0];
        float cv[24];
        unp8(*(const uint4*)cr,        cv);
        unp8(*(const uint4*)(cr + 8),  cv + 8);
        unp8(*(const uint4*)(cr + 16), cv + 16);
        float o[16];
        float s = cv[0] + cv[1] + cv[2] + cv[3] + cv[4];
        o[0] = s;
        #pragma unroll
        for (int j = 1; j < 16; ++j) { s += cv[j + 4] - cv[j - 1]; o[j] = s; }
        u16* dst = &sT1[r * S1 + s0];
        *(uint4*)dst = make_uint4(pk2(o[0], o[1]), pk2(o[2], o[3]),
                                  pk2(o[4], o[5]), pk2(o[6], o[7]));
        *(uint4*)(dst + 8) = make_uint4(pk2(o[8],  o[9]),  pk2(o[10], o[11]),
                                        pk2(o[12], o[13]), pk2(o[14], o[15]));
    }
    __syncthreads();

    // ---- P6b: vpool5 -> out; 16 row-groups of 4 x 16 col-quads (r4) ----
    for (int task = tid; task < 16 * 16; task += BLOCK) {
        int rg = task / 16, q = task & 15;
        int r0 = 4 * rg;
        const u16* hp = &sT1[r0 * S1 + 4 * q];
        float cs0 = 0.f, cs1 = 0.f, cs2 = 0.f, cs3 = 0.f;
        float a00, a01, a02, a03, a10, a11, a12, a13, a20, a21, a22, a23;
        #pragma unroll
        for (int k = 0; k < 5; ++k) {
            uint2 v = *(const uint2*)(hp + k * S1);
            float x0 = blo(v.x), x1 = bhi(v.x), x2 = blo(v.y), x3 = bhi(v.y);
            if (k == 0) { a00 = x0; a01 = x1; a02 = x2; a03 = x3; }
            if (k == 1) { a10 = x0; a11 = x1; a12 = x2; a13 = x3; }
            if (k == 2) { a20 = x0; a21 = x1; a22 = x2; a23 = x3; }
            cs0 += x0; cs1 += x1; cs2 += x2; cs3 += x3;
        }
        const float C25 = 1.f / 25.f;
        float* o0 = po + (size_t)(oy + r0) * 1024 + ox + 4 * q;
        *(float4*)o0 = make_float4(cs0 * C25, cs1 * C25, cs2 * C25, cs3 * C25);
        {
            uint2 v = *(const uint2*)(hp + 5 * S1);
            cs0 += blo(v.x) - a00; cs1 += bhi(v.x) - a01;
            cs2 += blo(v.y) - a02; cs3 += bhi(v.y) - a03;
        }
        *(float4*)(o0 + 1024) = make_float4(cs0 * C25, cs1 * C25, cs2 * C25, cs3 * C25);
        {
            uint2 v = *(const uint2*)(hp + 6 * S1);
            cs0 += blo(v.x) - a10; cs1 += bhi(v.x) - a11;
            cs2 += blo(v.y) - a12; cs3 += bhi(v.y) - a13;
        }
        *(float4*)(o0 + 2048) = make_float4(cs0 * C25, cs1 * C25, cs2 * C25, cs3 * C25);
        {
            uint2 v = *(const uint2*)(hp + 7 * S1);
            cs0 += blo(v.x) - a20; cs1 += bhi(v.x) - a21;
            cs2 += blo(v.y) - a22; cs3 += bhi(v.y) - a23;
        }
        *(float4*)(o0 + 3072) = make_float4(cs0 * C25, cs1 * C25, cs2 * C25, cs3 * C25);
    }
}

__global__ __launch_bounds__(BLOCK, 6)
void wrd_kernel(const float* __restrict__ img, float* __restrict__ out) {
    __shared__ u16 sLum[96 * SL];   // 19968 B
    __shared__ u16 sT1[96 * S1];    // 16896 B
    __shared__ u16 sDC[82 * S1];    // 14432 B  (d, then comb)

    int bid = blockIdx.x, nwg = gridDim.x;
    int flat = ((nwg & 7) == 0) ? ((bid & 7) * (nwg >> 3) + (bid >> 3)) : bid;
    const int b = flat >> 8;
    const int t = flat & 255;
    const int oy = (t >> 4) * 64, ox = (t & 15) * 64;

    const float* pR = img + (size_t)b * 3145728u;
    const float* pG = pR + 1048576;
    const float* pB = pR + 2097152;
    float* po = out + (size_t)b * 1048576u;

    bool edge = (ox == 0) | (oy == 0) | (ox == 960) | (oy == 960);
    if (edge) body<true >(pR, pG, pB, po, oy, ox, threadIdx.x, sLum, sT1, sDC);
    else      body<false>(pR, pG, pB, po, oy, ox, threadIdx.x, sLum, sT1, sDC);
}

extern "C" void kernel_launch(void* const* d_in, const int* in_sizes, int n_in,
                              void* d_out, int out_size, void* d_ws, size_t ws_size,
                              hipStream_t stream) {
    const float* img = (const float*)d_in[0];
    float* out = (float*)d_out;
    int Bn = in_sizes[0] / (3 * 1024 * 1024);
    int nwg = Bn * 256;
    hipLaunchKernelGGL(wrd_kernel, dim3(nwg), dim3(BLOCK), 0, stream, img, out);
}